// Round 7
// baseline (463.868 us; speedup 1.0000x reference)
//
#include <hip/hip_runtime.h>
#include <hip/hip_bf16.h>

#define B_ 4
#define N_ 2048
#define C_ 768
#define H_ 12
#define DH_ 64
#define HID_ 3072
#define ROWS_ (B_*N_)   // 8192

typedef short short8 __attribute__((ext_vector_type(8)));
typedef short short4v __attribute__((ext_vector_type(4)));
typedef unsigned short ushort4v __attribute__((ext_vector_type(4)));
typedef float f32x4 __attribute__((ext_vector_type(4)));

static __device__ __forceinline__ unsigned short f2bf(float f) {
    __hip_bfloat16 h = __float2bfloat16(f);
    unsigned short u;
    __builtin_memcpy(&u, &h, 2);
    return u;
}

// async global->LDS, 16B per lane; lds base must be wave-uniform (HW: base + lane*16)
static __device__ __forceinline__ void gload16(const unsigned short* g, unsigned short* l) {
    __builtin_amdgcn_global_load_lds(
        (const __attribute__((address_space(1))) unsigned int*)g,
        (__attribute__((address_space(3))) unsigned int*)l, 16, 0, 0);
}

// ---------------- LayerNorm: f32 row -> bf16 row ----------------
__global__ __launch_bounds__(256, 4) void ln_kernel(
    const float* __restrict__ x, const float* __restrict__ g,
    const float* __restrict__ bta, unsigned short* __restrict__ out) {
    int row = blockIdx.x;
    const float* xr = x + (size_t)row * C_;
    int t = threadIdx.x;
    float v0 = xr[t], v1 = xr[t + 256], v2 = xr[t + 512];
    float s = v0 + v1 + v2, ss = v0*v0 + v1*v1 + v2*v2;
    #pragma unroll
    for (int o = 32; o > 0; o >>= 1) { s += __shfl_down(s, o); ss += __shfl_down(ss, o); }
    __shared__ float red[10];
    int wid = t >> 6;
    if ((t & 63) == 0) { red[wid] = s; red[4 + wid] = ss; }
    __syncthreads();
    if (t == 0) {
        float S = red[0] + red[1] + red[2] + red[3];
        float SS = red[4] + red[5] + red[6] + red[7];
        float mu = S * (1.0f / C_);
        float var = SS * (1.0f / C_) - mu * mu;
        red[8] = mu; red[9] = rsqrtf(var + 1e-5f);
    }
    __syncthreads();
    float mu = red[8], rs = red[9];
    unsigned short* orow = out + (size_t)row * C_;
    orow[t]       = f2bf((v0 - mu) * rs * g[t]       + bta[t]);
    orow[t + 256] = f2bf((v1 - mu) * rs * g[t + 256] + bta[t + 256]);
    orow[t + 512] = f2bf((v2 - mu) * rs * g[t + 512] + bta[t + 512]);
}

// ------------- convert f32 [K][NN] -> bf16 transposed [NN][K] -------------
__global__ __launch_bounds__(256, 4) void convT_kernel(
    const float* __restrict__ in, unsigned short* __restrict__ out, int K, int NN) {
    __shared__ float tile[32][33];
    int n0 = blockIdx.x * 32, k0 = blockIdx.y * 32;
    int tx = threadIdx.x & 31, ty = threadIdx.x >> 5;   // ty 0..7
    #pragma unroll
    for (int j = 0; j < 4; j++)
        tile[ty + j*8][tx] = in[(size_t)(k0 + ty + j*8) * NN + n0 + tx];
    __syncthreads();
    #pragma unroll
    for (int j = 0; j < 4; j++)
        out[(size_t)(n0 + ty + j*8) * K + k0 + tx] = f2bf(tile[tx][ty + j*8]);
}

// ---------------- generic bf16 MFMA GEMM: C = A[M,K] @ Bt[NN,K]^T ----------------
// m97 structure: 128x128 tile, BK=64, linear LDS, global_load_lds width=16.
// EPI 0: scatter to q (scaled 0.125*log2e) / k       (qkv, NN=1536)
// EPI 1: out_f32 = res + acc + bias                  (proj, mlp2)
// EPI 2: out_bf16 = gelu(acc + bias)                 (mlp1)
// EPI 3: v^T GEMM: A = W_v^T [d][k], Bt = h_b [n][k] (batch = blockIdx.z);
//        out coalesced: vt[(b*H + d>>6)*DH + (d&63)][n]
template<int EPI>
__global__ __launch_bounds__(256, 3) void gemm_kernel(
    const unsigned short* __restrict__ A, const unsigned short* __restrict__ Bt,
    int K, int NN,
    const float* __restrict__ bias, const float* __restrict__ res,
    void* __restrict__ outp,
    unsigned short* __restrict__ qo, unsigned short* __restrict__ ko) {
    __shared__ unsigned short Al[128 * 64];   // linear: global_load_lds needs contiguous dest
    __shared__ unsigned short Bl[128 * 64];
    const int t = threadIdx.x;
    const int rowA0 = blockIdx.y * 128;
    const int colB0 = blockIdx.x * 128;
    const int wave = t >> 6, lane = t & 63;
    const int wm = wave >> 1, wn = wave & 1;
    const int lr = lane & 15, lg = lane >> 4;

    const unsigned short* Btb = (EPI == 3) ? Bt + (size_t)blockIdx.z * N_ * C_ : Bt;

    f32x4 acc[4][4];
    #pragma unroll
    for (int m = 0; m < 4; m++)
        #pragma unroll
        for (int n = 0; n < 4; n++)
            acc[m][n] = (f32x4){0.f, 0.f, 0.f, 0.f};

    // staging: wave owns rows [wave*32, wave*32+32); 4 issues x 8 rows x 1KB each.
    const int srow = wave * 32 + (lane >> 3);
    const int scol = (lane & 7) * 8;
    const unsigned short* Ag = A   + (size_t)(rowA0 + srow) * K + scol;
    const unsigned short* Bg = Btb + (size_t)(colB0 + srow) * K + scol;

    for (int kt = 0; kt < K; kt += 64) {
        __syncthreads();
        #pragma unroll
        for (int j = 0; j < 4; j++) {
            gload16(Ag + (size_t)j * 8 * K + kt, Al + (wave * 32 + j * 8) * 64);
            gload16(Bg + (size_t)j * 8 * K + kt, Bl + (wave * 32 + j * 8) * 64);
        }
        __syncthreads();   // drains vmcnt -> tiles ready
        #pragma unroll
        for (int kk = 0; kk < 2; kk++) {
            short8 af[4], bf[4];
            #pragma unroll
            for (int m = 0; m < 4; m++)
                af[m] = *(const short8*)(Al + (wm*64 + m*16 + lr) * 64 + kk*32 + lg*8);
            #pragma unroll
            for (int n = 0; n < 4; n++)
                bf[n] = *(const short8*)(Bl + (wn*64 + n*16 + lr) * 64 + kk*32 + lg*8);
            #pragma unroll
            for (int m = 0; m < 4; m++)
                #pragma unroll
                for (int n = 0; n < 4; n++)
                    acc[m][n] = __builtin_amdgcn_mfma_f32_16x16x32_bf16(af[m], bf[n], acc[m][n], 0, 0, 0);
        }
    }
    // epilogue: D layout col = lane&15, row = (lane>>4)*4 + reg   [m89]
    #pragma unroll
    for (int m = 0; m < 4; m++) {
        #pragma unroll
        for (int n = 0; n < 4; n++) {
            int gc = colB0 + wn*64 + n*16 + lr;
            #pragma unroll
            for (int r2 = 0; r2 < 4; r2++) {
                int gr = rowA0 + wm*64 + m*16 + lg*4 + r2;
                float val = acc[m][n][r2];
                if (EPI == 0) {
                    int which = gc >> 10;            // gc<1536: 0 = q, 1 = k (gc/C_ would branch 3-way)
                    int cc = gc - ((gc >= C_) ? C_ : 0);
                    int hh = cc >> 6, d = cc & 63;
                    int bb = gr >> 11, nn2 = gr & 2047;
                    size_t bh = (size_t)bb * H_ + hh;
                    // q pre-scaled by DH^-0.5 * log2(e) so softmax runs in exp2 domain
                    if (gc < C_) qo[(bh * N_ + nn2) * DH_ + d] = f2bf(val * 0.1803368801f);
                    else         ko[(bh * N_ + nn2) * DH_ + d] = f2bf(val);
                    (void)which;
                } else if (EPI == 1) {
                    size_t idx = (size_t)gr * NN + gc;
                    ((float*)outp)[idx] = res[idx] + val + bias[gc];
                } else if (EPI == 2) {
                    float xg = val + bias[gc];
                    float gl = 0.5f * xg * (1.0f + erff(xg * 0.7071067811865476f));
                    ((unsigned short*)outp)[(size_t)gr * NN + gc] = f2bf(gl);
                } else {
                    // v^T: row gr = head-dim index d in [0,768), col gc = n
                    size_t vrow = ((size_t)blockIdx.z * H_ + (gr >> 6)) * DH_ + (gr & 63);
                    ((unsigned short*)outp)[vrow * N_ + gc] = f2bf(val);
                }
            }
        }
    }
}

// ---------------- flash attention v3: swapped QK^T, P-in-register ----------------
// q[B,H,N,DH] (pre-scaled into exp2 domain), k[B,H,N,DH], vt[B,H,DH,N] -> o[B,N,C] bf16
// S^T = mfma(K,Q): lane owns ONE q-row (lr), 16 keys (cb*16+lg*4+i).
// Softmax: in-lane + 2 shfl. P stays in regs as PV B-operand; V^T read at matching
// permuted reduction slots (legal: same permutation on A and B k-dim).
__global__ __launch_bounds__(256, 6) void attn_kernel(
    const unsigned short* __restrict__ q, const unsigned short* __restrict__ k,
    const unsigned short* __restrict__ vt, unsigned short* __restrict__ o) {
    __shared__ unsigned short Kl[64 * 64];    // [key][dh], 128B rows, XOR-swizzled
    __shared__ unsigned short Vl[64 * 64];    // [dh][key], 128B rows, XOR-swizzled
    const int qt = blockIdx.x;
    const int bh = blockIdx.y;
    const int b = bh / H_, h = bh - b * H_;
    const size_t base = (size_t)bh * N_ * DH_;
    const int t = threadIdx.x, wave = t >> 6, lane = t & 63;
    const int lr = lane & 15, lg = lane >> 4;

    // Q fragment (B-operand for S^T): lane holds Q[qrow=lr][dh=ks*32+lg*8+j]
    const int qrow = qt * 64 + wave * 16 + lr;
    short8 qf[2];
    #pragma unroll
    for (int ks = 0; ks < 2; ks++)
        qf[ks] = *(const short8*)(q + base + (size_t)qrow * DH_ + ks * 32 + lg * 8);

    f32x4 oaccT[4];   // oaccT[db][i] = O[qrow=lr][dh=db*16+lg*4+i]
    #pragma unroll
    for (int d = 0; d < 4; d++) oaccT[d] = (f32x4){0.f, 0.f, 0.f, 0.f};
    float mi = -1e30f, li = 0.f;

    // staging geometry: row = t>>3 (0..31) and +32, col chunk = t&7
    const int sr0 = t >> 3, sr1 = sr0 + 32, scc = t & 7;
    const unsigned short* kg0 = k  + base + (size_t)sr0 * DH_ + scc * 8;
    const unsigned short* kg1 = k  + base + (size_t)sr1 * DH_ + scc * 8;
    const unsigned short* vg0 = vt + base + (size_t)sr0 * N_  + scc * 8;
    const unsigned short* vg1 = vt + base + (size_t)sr1 * N_  + scc * 8;
    const int sw0 = (scc * 16) ^ ((sr0 & 7) << 4);
    const int sw1 = (scc * 16) ^ ((sr1 & 7) << 4);

    // prologue: prefetch tile 0 into regs
    short8 kreg0 = *(const short8*)kg0, kreg1 = *(const short8*)kg1;
    short8 vreg0 = *(const short8*)vg0, vreg1 = *(const short8*)vg1;

    const int NT = N_ / 64;
    for (int kt2 = 0; kt2 < NT; kt2++) {
        __syncthreads();                       // all waves done reading prev tile
        *(short8*)((char*)Kl + sr0 * 128 + sw0) = kreg0;
        *(short8*)((char*)Kl + sr1 * 128 + sw1) = kreg1;
        *(short8*)((char*)Vl + sr0 * 128 + sw0) = vreg0;
        *(short8*)((char*)Vl + sr1 * 128 + sw1) = vreg1;
        __syncthreads();                       // tile visible
        if (kt2 + 1 < NT) {                    // prefetch next tile (hides under compute)
            kreg0 = *(const short8*)(kg0 + (size_t)(kt2 + 1) * 64 * DH_);
            kreg1 = *(const short8*)(kg1 + (size_t)(kt2 + 1) * 64 * DH_);
            vreg0 = *(const short8*)(vg0 + (size_t)(kt2 + 1) * 64);
            vreg1 = *(const short8*)(vg1 + (size_t)(kt2 + 1) * 64);
        }
        // S^T = K Q^T : s[cb][i] = S[qrow=lr][key=cb*16+lg*4+i]
        f32x4 s[4];
        #pragma unroll
        for (int cb = 0; cb < 4; cb++) {
            s[cb] = (f32x4){0.f, 0.f, 0.f, 0.f};
            int key = cb * 16 + lr;
            #pragma unroll
            for (int ks = 0; ks < 2; ks++) {
                int bytecol = ks * 64 + lg * 16;
                short8 kf = *(const short8*)((char*)Kl + key * 128 + (bytecol ^ ((key & 7) << 4)));
                s[cb] = __builtin_amdgcn_mfma_f32_16x16x32_bf16(kf, qf[ks], s[cb], 0, 0, 0);
            }
        }
        // in-lane row max over 16 values, then across 4 lane-groups (offsets 16,32)
        float mx = fmaxf(fmaxf(fmaxf(s[0][0], s[0][1]), fmaxf(s[0][2], s[0][3])),
                         fmaxf(fmaxf(s[1][0], s[1][1]), fmaxf(s[1][2], s[1][3])));
        mx = fmaxf(mx, fmaxf(fmaxf(fmaxf(s[2][0], s[2][1]), fmaxf(s[2][2], s[2][3])),
                             fmaxf(fmaxf(s[3][0], s[3][1]), fmaxf(s[3][2], s[3][3]))));
        mx = fmaxf(mx, __shfl_xor(mx, 16));
        mx = fmaxf(mx, __shfl_xor(mx, 32));
        // exact defer-max: rescale only when some lane's row max grew
        if (__any(mx > mi)) {
            float mn = fmaxf(mi, mx);
            float al = exp2f(mi - mn);
            mi = mn;
            li *= al;
            #pragma unroll
            for (int db = 0; db < 4; db++) oaccT[db] *= al;
        }
        // P = exp2(S - m) (stays in registers), row sum
        float rs = 0.f;
        #pragma unroll
        for (int cb = 0; cb < 4; cb++)
            #pragma unroll
            for (int i = 0; i < 4; i++) {
                float p = exp2f(s[cb][i] - mi);
                s[cb][i] = p;
                rs += p;
            }
        rs += __shfl_xor(rs, 16);
        rs += __shfl_xor(rs, 32);
        li += rs;
        // O^T += V^T P^T: B-frag slot (ks,lg,j) -> key (ks*2+(j>>2))*16+lg*4+(j&3)
        // = lane's own s registers; A-frag (V^T) read at the same permuted slots.
        #pragma unroll
        for (int ks = 0; ks < 2; ks++) {
            short8 pb;
            #pragma unroll
            for (int i = 0; i < 4; i++) {
                pb[i]     = (short)f2bf(s[2*ks][i]);
                pb[i + 4] = (short)f2bf(s[2*ks + 1][i]);
            }
            #pragma unroll
            for (int db = 0; db < 4; db++) {
                int dh = db * 16 + lr;
                int swz = (dh & 7) << 4;
                short4v v0 = *(const short4v*)((char*)Vl + dh * 128 + ((ks * 64 + lg * 8) ^ swz));
                short4v v1 = *(const short4v*)((char*)Vl + dh * 128 + ((ks * 64 + 32 + lg * 8) ^ swz));
                short8 vf;
                #pragma unroll
                for (int i = 0; i < 4; i++) { vf[i] = v0[i]; vf[i + 4] = v1[i]; }
                oaccT[db] = __builtin_amdgcn_mfma_f32_16x16x32_bf16(vf, pb, oaccT[db], 0, 0, 0);
            }
        }
    }
    // write: lane owns row qrow; cols h*64 + db*16 + lg*4 + {0..3} (8B packed)
    float inv = 1.0f / li;
    unsigned short* orow = o + ((size_t)b * N_ + qrow) * C_ + h * 64;
    #pragma unroll
    for (int db = 0; db < 4; db++) {
        ushort4v pk;
        #pragma unroll
        for (int i = 0; i < 4; i++) pk[i] = f2bf(oaccT[db][i] * inv);
        *(ushort4v*)(orow + db * 16 + lg * 4) = pk;
    }
}

extern "C" void kernel_launch(void* const* d_in, const int* in_sizes, int n_in,
                              void* d_out, int out_size, void* d_ws, size_t ws_size,
                              hipStream_t stream) {
    (void)in_sizes; (void)n_in; (void)out_size; (void)ws_size;
    const float* x      = (const float*)d_in[0];
    const float* ln1_g  = (const float*)d_in[1];
    const float* ln1_b  = (const float*)d_in[2];
    const float* w_qkv  = (const float*)d_in[3];
    const float* w_proj = (const float*)d_in[4];
    const float* b_proj = (const float*)d_in[5];
    const float* ln2_g  = (const float*)d_in[6];
    const float* ln2_b  = (const float*)d_in[7];
    const float* w1     = (const float*)d_in[8];
    const float* b1     = (const float*)d_in[9];
    const float* w2     = (const float*)d_in[10];
    const float* b2     = (const float*)d_in[11];
    float* out = (float*)d_out;

    char* ws = (char*)d_ws;
    size_t off = 0;
    auto alloc = [&](size_t bytes) {
        char* p = ws + off;
        off += (bytes + 255) & ~(size_t)255;
        return p;
    };
    unsigned short* hb     = (unsigned short*)alloc((size_t)ROWS_ * C_ * 2);
    unsigned short* wqkvT  = (unsigned short*)alloc((size_t)C_ * 3 * C_ * 2);
    unsigned short* wprojT = (unsigned short*)alloc((size_t)C_ * C_ * 2);
    unsigned short* w1T    = (unsigned short*)alloc((size_t)C_ * HID_ * 2);
    unsigned short* w2T    = (unsigned short*)alloc((size_t)HID_ * C_ * 2);
    unsigned short* uni    = (unsigned short*)alloc((size_t)ROWS_ * HID_ * 2); // q/k/vt/o alias mid
    unsigned short* qb  = uni;
    unsigned short* kb  = qb  + (size_t)B_ * H_ * N_ * DH_;
    unsigned short* vtb = kb  + (size_t)B_ * H_ * N_ * DH_;
    unsigned short* ob  = vtb + (size_t)B_ * H_ * N_ * DH_;
    unsigned short* mid = uni;   // reuse after attention is done

    // weight convert+transpose (bf16, [out][in])
    convT_kernel<<<dim3(3 * C_ / 32, C_ / 32), 256, 0, stream>>>(w_qkv, wqkvT, C_, 3 * C_);
    convT_kernel<<<dim3(C_ / 32, C_ / 32), 256, 0, stream>>>(w_proj, wprojT, C_, C_);
    convT_kernel<<<dim3(HID_ / 32, C_ / 32), 256, 0, stream>>>(w1, w1T, C_, HID_);
    convT_kernel<<<dim3(C_ / 32, HID_ / 32), 256, 0, stream>>>(w2, w2T, HID_, C_);

    // LN1 -> hb
    ln_kernel<<<ROWS_, 256, 0, stream>>>(x, ln1_g, ln1_b, hb);
    // QK GEMM (N=1536), scatter to q(scaled)/k
    gemm_kernel<0><<<dim3(2 * C_ / 128, ROWS_ / 128), 256, 0, stream>>>(
        hb, wqkvT, C_, 2 * C_, nullptr, nullptr, nullptr, qb, kb);
    // V^T GEMM: A = W_v^T (wqkvT rows 1536..2304), Bt = hb per batch -> vtb coalesced
    gemm_kernel<3><<<dim3(N_ / 128, C_ / 128, B_), 256, 0, stream>>>(
        wqkvT + (size_t)2 * C_ * C_, hb, C_, N_, nullptr, nullptr, (void*)vtb, nullptr, nullptr);
    // attention -> ob
    attn_kernel<<<dim3(N_ / 64, B_ * H_), 256, 0, stream>>>(qb, kb, vtb, ob);
    // proj + bias + residual -> d_out (f32 x1)
    gemm_kernel<1><<<dim3(C_ / 128, ROWS_ / 128), 256, 0, stream>>>(
        ob, wprojT, C_, C_, b_proj, x, (void*)out, nullptr, nullptr);
    // LN2 -> hb
    ln_kernel<<<ROWS_, 256, 0, stream>>>(out, ln2_g, ln2_b, hb);
    // MLP1 + gelu -> mid (bf16)
    gemm_kernel<2><<<dim3(HID_ / 128, ROWS_ / 128), 256, 0, stream>>>(
        hb, w1T, C_, HID_, b1, nullptr, (void*)mid, nullptr, nullptr);
    // MLP2 + bias + residual -> d_out
    gemm_kernel<1><<<dim3(C_ / 128, ROWS_ / 128), 256, 0, stream>>>(
        mid, w2T, HID_, C_, b2, out, (void*)out, nullptr, nullptr);
}

// Round 8
// 461.762 us; speedup vs baseline: 1.0046x; 1.0046x over previous
//
#include <hip/hip_runtime.h>
#include <hip/hip_bf16.h>

#define B_ 4
#define N_ 2048
#define C_ 768
#define H_ 12
#define DH_ 64
#define HID_ 3072
#define ROWS_ (B_*N_)   // 8192

typedef short short8 __attribute__((ext_vector_type(8)));
typedef short short4v __attribute__((ext_vector_type(4)));
typedef unsigned short ushort4v __attribute__((ext_vector_type(4)));
typedef float f32x4 __attribute__((ext_vector_type(4)));

static __device__ __forceinline__ unsigned short f2bf(float f) {
    __hip_bfloat16 h = __float2bfloat16(f);
    unsigned short u;
    __builtin_memcpy(&u, &h, 2);
    return u;
}

// async global->LDS, 16B per lane; lds base must be wave-uniform (HW: base + lane*16)
static __device__ __forceinline__ void gload16(const unsigned short* g, unsigned short* l) {
    __builtin_amdgcn_global_load_lds(
        (const __attribute__((address_space(1))) unsigned int*)g,
        (__attribute__((address_space(3))) unsigned int*)l, 16, 0, 0);
}

// ---------------- LayerNorm: f32 row -> bf16 row ----------------
__global__ __launch_bounds__(256, 4) void ln_kernel(
    const float* __restrict__ x, const float* __restrict__ g,
    const float* __restrict__ bta, unsigned short* __restrict__ out) {
    int row = blockIdx.x;
    const float* xr = x + (size_t)row * C_;
    int t = threadIdx.x;
    float v0 = xr[t], v1 = xr[t + 256], v2 = xr[t + 512];
    float s = v0 + v1 + v2, ss = v0*v0 + v1*v1 + v2*v2;
    #pragma unroll
    for (int o = 32; o > 0; o >>= 1) { s += __shfl_down(s, o); ss += __shfl_down(ss, o); }
    __shared__ float red[10];
    int wid = t >> 6;
    if ((t & 63) == 0) { red[wid] = s; red[4 + wid] = ss; }
    __syncthreads();
    if (t == 0) {
        float S = red[0] + red[1] + red[2] + red[3];
        float SS = red[4] + red[5] + red[6] + red[7];
        float mu = S * (1.0f / C_);
        float var = SS * (1.0f / C_) - mu * mu;
        red[8] = mu; red[9] = rsqrtf(var + 1e-5f);
    }
    __syncthreads();
    float mu = red[8], rs = red[9];
    unsigned short* orow = out + (size_t)row * C_;
    orow[t]       = f2bf((v0 - mu) * rs * g[t]       + bta[t]);
    orow[t + 256] = f2bf((v1 - mu) * rs * g[t + 256] + bta[t + 256]);
    orow[t + 512] = f2bf((v2 - mu) * rs * g[t + 512] + bta[t + 512]);
}

// ------------- convert f32 [K][NN] -> bf16 transposed [NN][K] -------------
__global__ __launch_bounds__(256, 4) void convT_kernel(
    const float* __restrict__ in, unsigned short* __restrict__ out, int K, int NN) {
    __shared__ float tile[32][33];
    int n0 = blockIdx.x * 32, k0 = blockIdx.y * 32;
    int tx = threadIdx.x & 31, ty = threadIdx.x >> 5;   // ty 0..7
    #pragma unroll
    for (int j = 0; j < 4; j++)
        tile[ty + j*8][tx] = in[(size_t)(k0 + ty + j*8) * NN + n0 + tx];
    __syncthreads();
    #pragma unroll
    for (int j = 0; j < 4; j++)
        out[(size_t)(n0 + ty + j*8) * K + k0 + tx] = f2bf(tile[tx][ty + j*8]);
}

// ---------------- generic bf16 MFMA GEMM: C = A[M,K] @ Bt[NN,K]^T ----------------
// m97 structure: 128x128 tile, BK=64, linear LDS, global_load_lds width=16.
// EPI 0: scatter to q (scaled 0.125*log2e) / k       (qkv, NN=1536)
// EPI 1: out_f32 = res + acc + bias                  (proj, mlp2)
// EPI 2: out_bf16 = gelu(acc + bias)                 (mlp1)
// EPI 3: v^T GEMM: A = W_v^T [d][k], Bt = h_b [n][k] (batch = blockIdx.z);
//        out coalesced: vt[(b*H + d>>6)*DH + (d&63)][n]
template<int EPI>
__global__ __launch_bounds__(256, 3) void gemm_kernel(
    const unsigned short* __restrict__ A, const unsigned short* __restrict__ Bt,
    int K, int NN,
    const float* __restrict__ bias, const float* __restrict__ res,
    void* __restrict__ outp,
    unsigned short* __restrict__ qo, unsigned short* __restrict__ ko) {
    __shared__ unsigned short Al[128 * 64];   // linear: global_load_lds needs contiguous dest
    __shared__ unsigned short Bl[128 * 64];
    const int t = threadIdx.x;
    const int rowA0 = blockIdx.y * 128;
    const int colB0 = blockIdx.x * 128;
    const int wave = t >> 6, lane = t & 63;
    const int wm = wave >> 1, wn = wave & 1;
    const int lr = lane & 15, lg = lane >> 4;

    const unsigned short* Btb = (EPI == 3) ? Bt + (size_t)blockIdx.z * N_ * C_ : Bt;

    f32x4 acc[4][4];
    #pragma unroll
    for (int m = 0; m < 4; m++)
        #pragma unroll
        for (int n = 0; n < 4; n++)
            acc[m][n] = (f32x4){0.f, 0.f, 0.f, 0.f};

    // staging: wave owns rows [wave*32, wave*32+32); 4 issues x 8 rows x 1KB each.
    const int srow = wave * 32 + (lane >> 3);
    const int scol = (lane & 7) * 8;
    const unsigned short* Ag = A   + (size_t)(rowA0 + srow) * K + scol;
    const unsigned short* Bg = Btb + (size_t)(colB0 + srow) * K + scol;

    for (int kt = 0; kt < K; kt += 64) {
        __syncthreads();
        #pragma unroll
        for (int j = 0; j < 4; j++) {
            gload16(Ag + (size_t)j * 8 * K + kt, Al + (wave * 32 + j * 8) * 64);
            gload16(Bg + (size_t)j * 8 * K + kt, Bl + (wave * 32 + j * 8) * 64);
        }
        __syncthreads();   // drains vmcnt -> tiles ready
        #pragma unroll
        for (int kk = 0; kk < 2; kk++) {
            short8 af[4], bf[4];
            #pragma unroll
            for (int m = 0; m < 4; m++)
                af[m] = *(const short8*)(Al + (wm*64 + m*16 + lr) * 64 + kk*32 + lg*8);
            #pragma unroll
            for (int n = 0; n < 4; n++)
                bf[n] = *(const short8*)(Bl + (wn*64 + n*16 + lr) * 64 + kk*32 + lg*8);
            #pragma unroll
            for (int m = 0; m < 4; m++)
                #pragma unroll
                for (int n = 0; n < 4; n++)
                    acc[m][n] = __builtin_amdgcn_mfma_f32_16x16x32_bf16(af[m], bf[n], acc[m][n], 0, 0, 0);
        }
    }
    // epilogue: D layout col = lane&15, row = (lane>>4)*4 + reg   [m89]
    #pragma unroll
    for (int m = 0; m < 4; m++) {
        #pragma unroll
        for (int n = 0; n < 4; n++) {
            int gc = colB0 + wn*64 + n*16 + lr;
            #pragma unroll
            for (int r2 = 0; r2 < 4; r2++) {
                int gr = rowA0 + wm*64 + m*16 + lg*4 + r2;
                float val = acc[m][n][r2];
                if (EPI == 0) {
                    int cc = gc - ((gc >= C_) ? C_ : 0);
                    int hh = cc >> 6, d = cc & 63;
                    int bb = gr >> 11, nn2 = gr & 2047;
                    size_t bh = (size_t)bb * H_ + hh;
                    // q pre-scaled by DH^-0.5 * log2(e) so softmax runs in exp2 domain
                    if (gc < C_) qo[(bh * N_ + nn2) * DH_ + d] = f2bf(val * 0.1803368801f);
                    else         ko[(bh * N_ + nn2) * DH_ + d] = f2bf(val);
                } else if (EPI == 1) {
                    size_t idx = (size_t)gr * NN + gc;
                    ((float*)outp)[idx] = res[idx] + val + bias[gc];
                } else if (EPI == 2) {
                    float xg = val + bias[gc];
                    float gl = 0.5f * xg * (1.0f + erff(xg * 0.7071067811865476f));
                    ((unsigned short*)outp)[(size_t)gr * NN + gc] = f2bf(gl);
                } else {
                    // v^T: row gr = head-dim index d in [0,768), col gc = n
                    size_t vrow = ((size_t)blockIdx.z * H_ + (gr >> 6)) * DH_ + (gr & 63);
                    ((unsigned short*)outp)[vrow * N_ + gc] = f2bf(val);
                }
            }
        }
    }
}

// ---------------- flash attention v4: swapped QK^T, P-in-register, XCD-chunked ----------------
// 1D grid 1536 = 8 XCD chunks x 6 bh x 32 q-tiles. XCD c (= wgid&7) owns bh in
// [c*6, c*6+6) entirely -> per-XCD KV working set 6 x 512KB = 3MB < 4MB L2.
__global__ __launch_bounds__(256, 6) void attn_kernel(
    const unsigned short* __restrict__ q, const unsigned short* __restrict__ k,
    const unsigned short* __restrict__ vt, unsigned short* __restrict__ o) {
    __shared__ unsigned short Kl[64 * 64];    // [key][dh], 128B rows, XOR-swizzled
    __shared__ unsigned short Vl[64 * 64];    // [dh][key], 128B rows, XOR-swizzled
    const int wgid = blockIdx.x;
    const int c = wgid & 7, idx = wgid >> 3;
    const int bh = c * 6 + (idx >> 5);        // 48 = 8 XCDs x 6 groups
    const int qt = idx & 31;                  // 32 q-tiles of 64 rows
    const int b = bh / H_, h = bh - b * H_;
    const size_t base = (size_t)bh * N_ * DH_;
    const int t = threadIdx.x, wave = t >> 6, lane = t & 63;
    const int lr = lane & 15, lg = lane >> 4;

    // Q fragment (B-operand for S^T): lane holds Q[qrow=lr][dh=ks*32+lg*8+j]
    const int qrow = qt * 64 + wave * 16 + lr;
    short8 qf[2];
    #pragma unroll
    for (int ks = 0; ks < 2; ks++)
        qf[ks] = *(const short8*)(q + base + (size_t)qrow * DH_ + ks * 32 + lg * 8);

    f32x4 oaccT[4];   // oaccT[db][i] = O[qrow=lr][dh=db*16+lg*4+i]
    #pragma unroll
    for (int d = 0; d < 4; d++) oaccT[d] = (f32x4){0.f, 0.f, 0.f, 0.f};
    float mi = -1e30f, li = 0.f;

    // staging geometry: row = t>>3 (0..31) and +32, col chunk = t&7
    const int sr0 = t >> 3, sr1 = sr0 + 32, scc = t & 7;
    const unsigned short* kg0 = k  + base + (size_t)sr0 * DH_ + scc * 8;
    const unsigned short* kg1 = k  + base + (size_t)sr1 * DH_ + scc * 8;
    const unsigned short* vg0 = vt + base + (size_t)sr0 * N_  + scc * 8;
    const unsigned short* vg1 = vt + base + (size_t)sr1 * N_  + scc * 8;
    const int sw0 = (scc * 16) ^ ((sr0 & 7) << 4);
    const int sw1 = (scc * 16) ^ ((sr1 & 7) << 4);

    // prologue: prefetch tile 0 into regs
    short8 kreg0 = *(const short8*)kg0, kreg1 = *(const short8*)kg1;
    short8 vreg0 = *(const short8*)vg0, vreg1 = *(const short8*)vg1;

    const int NT = N_ / 64;
    for (int kt2 = 0; kt2 < NT; kt2++) {
        __syncthreads();                       // all waves done reading prev tile
        *(short8*)((char*)Kl + sr0 * 128 + sw0) = kreg0;
        *(short8*)((char*)Kl + sr1 * 128 + sw1) = kreg1;
        *(short8*)((char*)Vl + sr0 * 128 + sw0) = vreg0;
        *(short8*)((char*)Vl + sr1 * 128 + sw1) = vreg1;
        __syncthreads();                       // tile visible
        if (kt2 + 1 < NT) {                    // prefetch next tile (hides under compute)
            kreg0 = *(const short8*)(kg0 + (size_t)(kt2 + 1) * 64 * DH_);
            kreg1 = *(const short8*)(kg1 + (size_t)(kt2 + 1) * 64 * DH_);
            vreg0 = *(const short8*)(vg0 + (size_t)(kt2 + 1) * 64);
            vreg1 = *(const short8*)(vg1 + (size_t)(kt2 + 1) * 64);
        }
        // S^T = K Q^T : s[cb][i] = S[qrow=lr][key=cb*16+lg*4+i]
        f32x4 s[4];
        #pragma unroll
        for (int cb = 0; cb < 4; cb++) {
            s[cb] = (f32x4){0.f, 0.f, 0.f, 0.f};
            int key = cb * 16 + lr;
            #pragma unroll
            for (int ks = 0; ks < 2; ks++) {
                int bytecol = ks * 64 + lg * 16;
                short8 kf = *(const short8*)((char*)Kl + key * 128 + (bytecol ^ ((key & 7) << 4)));
                s[cb] = __builtin_amdgcn_mfma_f32_16x16x32_bf16(kf, qf[ks], s[cb], 0, 0, 0);
            }
        }
        // in-lane row max over 16 values, then across 4 lane-groups (offsets 16,32)
        float mx = fmaxf(fmaxf(fmaxf(s[0][0], s[0][1]), fmaxf(s[0][2], s[0][3])),
                         fmaxf(fmaxf(s[1][0], s[1][1]), fmaxf(s[1][2], s[1][3])));
        mx = fmaxf(mx, fmaxf(fmaxf(fmaxf(s[2][0], s[2][1]), fmaxf(s[2][2], s[2][3])),
                             fmaxf(fmaxf(s[3][0], s[3][1]), fmaxf(s[3][2], s[3][3]))));
        mx = fmaxf(mx, __shfl_xor(mx, 16));
        mx = fmaxf(mx, __shfl_xor(mx, 32));
        // exact defer-max: rescale only when some lane's row max grew
        if (__any(mx > mi)) {
            float mn = fmaxf(mi, mx);
            float al = exp2f(mi - mn);
            mi = mn;
            li *= al;
            #pragma unroll
            for (int db = 0; db < 4; db++) oaccT[db] *= al;
        }
        // P = exp2(S - m) (stays in registers), row sum
        float rs = 0.f;
        #pragma unroll
        for (int cb = 0; cb < 4; cb++)
            #pragma unroll
            for (int i = 0; i < 4; i++) {
                float p = exp2f(s[cb][i] - mi);
                s[cb][i] = p;
                rs += p;
            }
        rs += __shfl_xor(rs, 16);
        rs += __shfl_xor(rs, 32);
        li += rs;
        // O^T += V^T P^T: B-frag slot (ks,lg,j) -> key (ks*2+(j>>2))*16+lg*4+(j&3)
        // = lane's own s registers; A-frag (V^T) read at the same permuted slots.
        #pragma unroll
        for (int ks = 0; ks < 2; ks++) {
            short8 pb;
            #pragma unroll
            for (int i = 0; i < 4; i++) {
                pb[i]     = (short)f2bf(s[2*ks][i]);
                pb[i + 4] = (short)f2bf(s[2*ks + 1][i]);
            }
            #pragma unroll
            for (int db = 0; db < 4; db++) {
                int dh = db * 16 + lr;
                int swz = (dh & 7) << 4;
                short4v v0 = *(const short4v*)((char*)Vl + dh * 128 + ((ks * 64 + lg * 8) ^ swz));
                short4v v1 = *(const short4v*)((char*)Vl + dh * 128 + ((ks * 64 + 32 + lg * 8) ^ swz));
                short8 vf;
                #pragma unroll
                for (int i = 0; i < 4; i++) { vf[i] = v0[i]; vf[i + 4] = v1[i]; }
                oaccT[db] = __builtin_amdgcn_mfma_f32_16x16x32_bf16(vf, pb, oaccT[db], 0, 0, 0);
            }
        }
    }
    // write: lane owns row qrow; cols h*64 + db*16 + lg*4 + {0..3} (8B packed)
    float inv = 1.0f / li;
    unsigned short* orow = o + ((size_t)b * N_ + qrow) * C_ + h * 64;
    #pragma unroll
    for (int db = 0; db < 4; db++) {
        ushort4v pk;
        #pragma unroll
        for (int i = 0; i < 4; i++) pk[i] = f2bf(oaccT[db][i] * inv);
        *(ushort4v*)(orow + db * 16 + lg * 4) = pk;
    }
}

extern "C" void kernel_launch(void* const* d_in, const int* in_sizes, int n_in,
                              void* d_out, int out_size, void* d_ws, size_t ws_size,
                              hipStream_t stream) {
    (void)in_sizes; (void)n_in; (void)out_size; (void)ws_size;
    const float* x      = (const float*)d_in[0];
    const float* ln1_g  = (const float*)d_in[1];
    const float* ln1_b  = (const float*)d_in[2];
    const float* w_qkv  = (const float*)d_in[3];
    const float* w_proj = (const float*)d_in[4];
    const float* b_proj = (const float*)d_in[5];
    const float* ln2_g  = (const float*)d_in[6];
    const float* ln2_b  = (const float*)d_in[7];
    const float* w1     = (const float*)d_in[8];
    const float* b1     = (const float*)d_in[9];
    const float* w2     = (const float*)d_in[10];
    const float* b2     = (const float*)d_in[11];
    float* out = (float*)d_out;

    char* ws = (char*)d_ws;
    size_t off = 0;
    auto alloc = [&](size_t bytes) {
        char* p = ws + off;
        off += (bytes + 255) & ~(size_t)255;
        return p;
    };
    unsigned short* hb     = (unsigned short*)alloc((size_t)ROWS_ * C_ * 2);
    unsigned short* wqkvT  = (unsigned short*)alloc((size_t)C_ * 3 * C_ * 2);
    unsigned short* wprojT = (unsigned short*)alloc((size_t)C_ * C_ * 2);
    unsigned short* w1T    = (unsigned short*)alloc((size_t)C_ * HID_ * 2);
    unsigned short* w2T    = (unsigned short*)alloc((size_t)HID_ * C_ * 2);
    unsigned short* uni    = (unsigned short*)alloc((size_t)ROWS_ * HID_ * 2); // q/k/vt/o alias mid
    unsigned short* qb  = uni;
    unsigned short* kb  = qb  + (size_t)B_ * H_ * N_ * DH_;
    unsigned short* vtb = kb  + (size_t)B_ * H_ * N_ * DH_;
    unsigned short* ob  = vtb + (size_t)B_ * H_ * N_ * DH_;
    unsigned short* mid = uni;   // reuse after attention is done

    // weight convert+transpose (bf16, [out][in])
    convT_kernel<<<dim3(3 * C_ / 32, C_ / 32), 256, 0, stream>>>(w_qkv, wqkvT, C_, 3 * C_);
    convT_kernel<<<dim3(C_ / 32, C_ / 32), 256, 0, stream>>>(w_proj, wprojT, C_, C_);
    convT_kernel<<<dim3(HID_ / 32, C_ / 32), 256, 0, stream>>>(w1, w1T, C_, HID_);
    convT_kernel<<<dim3(C_ / 32, HID_ / 32), 256, 0, stream>>>(w2, w2T, HID_, C_);

    // LN1 -> hb
    ln_kernel<<<ROWS_, 256, 0, stream>>>(x, ln1_g, ln1_b, hb);
    // QK GEMM (N=1536), scatter to q(scaled)/k
    gemm_kernel<0><<<dim3(2 * C_ / 128, ROWS_ / 128), 256, 0, stream>>>(
        hb, wqkvT, C_, 2 * C_, nullptr, nullptr, nullptr, qb, kb);
    // V^T GEMM: A = W_v^T (wqkvT rows 1536..2304), Bt = hb per batch -> vtb coalesced
    gemm_kernel<3><<<dim3(N_ / 128, C_ / 128, B_), 256, 0, stream>>>(
        wqkvT + (size_t)2 * C_ * C_, hb, C_, N_, nullptr, nullptr, (void*)vtb, nullptr, nullptr);
    // attention -> ob  (1D grid, XCD-chunked)
    attn_kernel<<<dim3(8 * 6 * (N_ / 64)), 256, 0, stream>>>(qb, kb, vtb, ob);
    // proj + bias + residual -> d_out (f32 x1)
    gemm_kernel<1><<<dim3(C_ / 128, ROWS_ / 128), 256, 0, stream>>>(
        ob, wprojT, C_, C_, b_proj, x, (void*)out, nullptr, nullptr);
    // LN2 -> hb
    ln_kernel<<<ROWS_, 256, 0, stream>>>(out, ln2_g, ln2_b, hb);
    // MLP1 + gelu -> mid (bf16)
    gemm_kernel<2><<<dim3(HID_ / 128, ROWS_ / 128), 256, 0, stream>>>(
        hb, w1T, C_, HID_, b1, nullptr, (void*)mid, nullptr, nullptr);
    // MLP2 + bias + residual -> d_out
    gemm_kernel<1><<<dim3(C_ / 128, ROWS_ / 128), 256, 0, stream>>>(
        mid, w2T, HID_, C_, b2, out, (void*)out, nullptr, nullptr);
}

// Round 10
// 445.152 us; speedup vs baseline: 1.0420x; 1.0373x over previous
//
#include <hip/hip_runtime.h>
#include <hip/hip_bf16.h>

#define B_ 4
#define N_ 2048
#define C_ 768
#define H_ 12
#define DH_ 64
#define HID_ 3072
#define ROWS_ (B_*N_)   // 8192

typedef short short8 __attribute__((ext_vector_type(8)));
typedef short short4v __attribute__((ext_vector_type(4)));
typedef unsigned short ushort4v __attribute__((ext_vector_type(4)));
typedef float f32x4 __attribute__((ext_vector_type(4)));

static __device__ __forceinline__ unsigned short f2bf(float f) {
    __hip_bfloat16 h = __float2bfloat16(f);
    unsigned short u;
    __builtin_memcpy(&u, &h, 2);
    return u;
}

// async global->LDS, 16B per lane; lds base must be wave-uniform (HW: base + lane*16)
static __device__ __forceinline__ void gload16(const unsigned short* g, unsigned short* l) {
    __builtin_amdgcn_global_load_lds(
        (const __attribute__((address_space(1))) unsigned int*)g,
        (__attribute__((address_space(3))) unsigned int*)l, 16, 0, 0);
}

// ---------------- LayerNorm: f32 row -> bf16 row ----------------
__global__ __launch_bounds__(256, 4) void ln_kernel(
    const float* __restrict__ x, const float* __restrict__ g,
    const float* __restrict__ bta, unsigned short* __restrict__ out) {
    int row = blockIdx.x;
    const float* xr = x + (size_t)row * C_;
    int t = threadIdx.x;
    float v0 = xr[t], v1 = xr[t + 256], v2 = xr[t + 512];
    float s = v0 + v1 + v2, ss = v0*v0 + v1*v1 + v2*v2;
    #pragma unroll
    for (int o = 32; o > 0; o >>= 1) { s += __shfl_down(s, o); ss += __shfl_down(ss, o); }
    __shared__ float red[10];
    int wid = t >> 6;
    if ((t & 63) == 0) { red[wid] = s; red[4 + wid] = ss; }
    __syncthreads();
    if (t == 0) {
        float S = red[0] + red[1] + red[2] + red[3];
        float SS = red[4] + red[5] + red[6] + red[7];
        float mu = S * (1.0f / C_);
        float var = SS * (1.0f / C_) - mu * mu;
        red[8] = mu; red[9] = rsqrtf(var + 1e-5f);
    }
    __syncthreads();
    float mu = red[8], rs = red[9];
    unsigned short* orow = out + (size_t)row * C_;
    orow[t]       = f2bf((v0 - mu) * rs * g[t]       + bta[t]);
    orow[t + 256] = f2bf((v1 - mu) * rs * g[t + 256] + bta[t + 256]);
    orow[t + 512] = f2bf((v2 - mu) * rs * g[t + 512] + bta[t + 512]);
}

// ------------- convert f32 [K][NN] -> bf16 transposed [NN][K] -------------
__global__ __launch_bounds__(256, 4) void convT_kernel(
    const float* __restrict__ in, unsigned short* __restrict__ out, int K, int NN) {
    __shared__ float tile[32][33];
    int n0 = blockIdx.x * 32, k0 = blockIdx.y * 32;
    int tx = threadIdx.x & 31, ty = threadIdx.x >> 5;   // ty 0..7
    #pragma unroll
    for (int j = 0; j < 4; j++)
        tile[ty + j*8][tx] = in[(size_t)(k0 + ty + j*8) * NN + n0 + tx];
    __syncthreads();
    #pragma unroll
    for (int j = 0; j < 4; j++)
        out[(size_t)(n0 + ty + j*8) * K + k0 + tx] = f2bf(tile[tx][ty + j*8]);
}

// ---------------- generic bf16 MFMA GEMM: C = A[M,K] @ Bt[NN,K]^T ----------------
// m97 structure: 128x128 tile, BK=64, linear LDS, global_load_lds width=16.
// EPI 0: scatter to q (scaled 0.125*log2e) / k       (qkv, NN=1536)
// EPI 1: out_f32 = res + acc + bias                  (proj, mlp2)
// EPI 2: out_bf16 = gelu(acc + bias)                 (mlp1)
// EPI 3: v^T GEMM: A = W_v^T [d][k], Bt = h_b [n][k] (batch = blockIdx.z);
//        out coalesced: vt[(b*H + d>>6)*DH + (d&63)][n]
template<int EPI>
__global__ __launch_bounds__(256, 3) void gemm_kernel(
    const unsigned short* __restrict__ A, const unsigned short* __restrict__ Bt,
    int K, int NN,
    const float* __restrict__ bias, const float* __restrict__ res,
    void* __restrict__ outp,
    unsigned short* __restrict__ qo, unsigned short* __restrict__ ko) {
    __shared__ unsigned short Al[128 * 64];   // linear: global_load_lds needs contiguous dest
    __shared__ unsigned short Bl[128 * 64];
    const int t = threadIdx.x;
    const int rowA0 = blockIdx.y * 128;
    const int colB0 = blockIdx.x * 128;
    const int wave = t >> 6, lane = t & 63;
    const int wm = wave >> 1, wn = wave & 1;
    const int lr = lane & 15, lg = lane >> 4;

    const unsigned short* Btb = (EPI == 3) ? Bt + (size_t)blockIdx.z * N_ * C_ : Bt;

    f32x4 acc[4][4];
    #pragma unroll
    for (int m = 0; m < 4; m++)
        #pragma unroll
        for (int n = 0; n < 4; n++)
            acc[m][n] = (f32x4){0.f, 0.f, 0.f, 0.f};

    // staging: wave owns rows [wave*32, wave*32+32); 4 issues x 8 rows x 1KB each.
    const int srow = wave * 32 + (lane >> 3);
    const int scol = (lane & 7) * 8;
    const unsigned short* Ag = A   + (size_t)(rowA0 + srow) * K + scol;
    const unsigned short* Bg = Btb + (size_t)(colB0 + srow) * K + scol;

    for (int kt = 0; kt < K; kt += 64) {
        __syncthreads();
        #pragma unroll
        for (int j = 0; j < 4; j++) {
            gload16(Ag + (size_t)j * 8 * K + kt, Al + (wave * 32 + j * 8) * 64);
            gload16(Bg + (size_t)j * 8 * K + kt, Bl + (wave * 32 + j * 8) * 64);
        }
        __syncthreads();   // drains vmcnt -> tiles ready
        #pragma unroll
        for (int kk = 0; kk < 2; kk++) {
            short8 af[4], bf[4];
            #pragma unroll
            for (int m = 0; m < 4; m++)
                af[m] = *(const short8*)(Al + (wm*64 + m*16 + lr) * 64 + kk*32 + lg*8);
            #pragma unroll
            for (int n = 0; n < 4; n++)
                bf[n] = *(const short8*)(Bl + (wn*64 + n*16 + lr) * 64 + kk*32 + lg*8);
            #pragma unroll
            for (int m = 0; m < 4; m++)
                #pragma unroll
                for (int n = 0; n < 4; n++)
                    acc[m][n] = __builtin_amdgcn_mfma_f32_16x16x32_bf16(af[m], bf[n], acc[m][n], 0, 0, 0);
        }
    }
    // epilogue: D layout col = lane&15, row = (lane>>4)*4 + reg   [m89]
    #pragma unroll
    for (int m = 0; m < 4; m++) {
        #pragma unroll
        for (int n = 0; n < 4; n++) {
            int gc = colB0 + wn*64 + n*16 + lr;
            #pragma unroll
            for (int r2 = 0; r2 < 4; r2++) {
                int gr = rowA0 + wm*64 + m*16 + lg*4 + r2;
                float val = acc[m][n][r2];
                if (EPI == 0) {
                    int cc = gc - ((gc >= C_) ? C_ : 0);
                    int hh = cc >> 6, d = cc & 63;
                    int bb = gr >> 11, nn2 = gr & 2047;
                    size_t bh = (size_t)bb * H_ + hh;
                    // q pre-scaled by DH^-0.5 * log2(e) so softmax runs in exp2 domain
                    if (gc < C_) qo[(bh * N_ + nn2) * DH_ + d] = f2bf(val * 0.1803368801f);
                    else         ko[(bh * N_ + nn2) * DH_ + d] = f2bf(val);
                } else if (EPI == 1) {
                    size_t idx = (size_t)gr * NN + gc;
                    ((float*)outp)[idx] = res[idx] + val + bias[gc];
                } else if (EPI == 2) {
                    float xg = val + bias[gc];
                    float gl = 0.5f * xg * (1.0f + erff(xg * 0.7071067811865476f));
                    ((unsigned short*)outp)[(size_t)gr * NN + gc] = f2bf(gl);
                } else {
                    // v^T: row gr = head-dim index d in [0,768), col gc = n
                    size_t vrow = ((size_t)blockIdx.z * H_ + (gr >> 6)) * DH_ + (gr & 63);
                    ((unsigned short*)outp)[vrow * N_ + gc] = f2bf(val);
                }
            }
        }
    }
}

// ---------------- flash attention v5: QBLK=128, 2 row-groups/wave, shared K/V frags ----------------
// 1D grid 768 = 8 XCD chunks x 6 bh x 16 q-tiles of 128 rows. Each wave: 32 q-rows
// (2x16 groups). V-fragments read ONCE per tile and feed both groups' PV MFMAs;
// staging + barriers amortized 2x vs QBLK=64. Swapped QK^T keeps softmax in-lane.
__global__ __launch_bounds__(256, 3) void attn_kernel(
    const unsigned short* __restrict__ q, const unsigned short* __restrict__ k,
    const unsigned short* __restrict__ vt, unsigned short* __restrict__ o) {
    __shared__ unsigned short Kl[64 * 64];    // [key][dh], 128B rows, XOR-swizzled
    __shared__ unsigned short Vl[64 * 64];    // [dh][key], 128B rows, XOR-swizzled
    const int wgid = blockIdx.x;
    const int c = wgid & 7, idx = wgid >> 3;  // 768 = 8 x 96
    const int bh = c * 6 + (idx >> 4);        // XCD c owns bh in [c*6, c*6+6)
    const int qt = idx & 15;                  // 16 q-tiles of 128 rows
    const int b = bh / H_, h = bh - b * H_;
    const size_t base = (size_t)bh * N_ * DH_;
    const int t = threadIdx.x, wave = t >> 6, lane = t & 63;
    const int lr = lane & 15, lg = lane >> 4;

    // Q fragments (B-operand for S^T): group ro -> qrow = qt*128 + wave*32 + ro*16 + lr
    short8 qf[2][2];
    #pragma unroll
    for (int ro = 0; ro < 2; ro++) {
        int qrow = qt * 128 + wave * 32 + ro * 16 + lr;
        #pragma unroll
        for (int ks = 0; ks < 2; ks++)
            qf[ro][ks] = *(const short8*)(q + base + (size_t)qrow * DH_ + ks * 32 + lg * 8);
    }

    f32x4 oaccT[2][4];   // oaccT[ro][db][i] = O[qrow(ro)][dh=db*16+lg*4+i]
    float mi[2] = {-1e30f, -1e30f}, li[2] = {0.f, 0.f};
    #pragma unroll
    for (int ro = 0; ro < 2; ro++)
        #pragma unroll
        for (int d = 0; d < 4; d++) oaccT[ro][d] = (f32x4){0.f, 0.f, 0.f, 0.f};

    // staging geometry: row = t>>3 (0..31) and +32, col chunk = t&7
    const int sr0 = t >> 3, sr1 = sr0 + 32, scc = t & 7;
    const unsigned short* kg0 = k  + base + (size_t)sr0 * DH_ + scc * 8;
    const unsigned short* kg1 = k  + base + (size_t)sr1 * DH_ + scc * 8;
    const unsigned short* vg0 = vt + base + (size_t)sr0 * N_  + scc * 8;
    const unsigned short* vg1 = vt + base + (size_t)sr1 * N_  + scc * 8;
    const int sw0 = (scc * 16) ^ ((sr0 & 7) << 4);
    const int sw1 = (scc * 16) ^ ((sr1 & 7) << 4);

    // prologue: prefetch tile 0 into regs
    short8 kreg0 = *(const short8*)kg0, kreg1 = *(const short8*)kg1;
    short8 vreg0 = *(const short8*)vg0, vreg1 = *(const short8*)vg1;

    const int NT = N_ / 64;
    for (int kt2 = 0; kt2 < NT; kt2++) {
        __syncthreads();                       // all waves done reading prev tile
        *(short8*)((char*)Kl + sr0 * 128 + sw0) = kreg0;
        *(short8*)((char*)Kl + sr1 * 128 + sw1) = kreg1;
        *(short8*)((char*)Vl + sr0 * 128 + sw0) = vreg0;
        *(short8*)((char*)Vl + sr1 * 128 + sw1) = vreg1;
        __syncthreads();                       // tile visible
        if (kt2 + 1 < NT) {                    // prefetch next tile (hides under compute)
            kreg0 = *(const short8*)(kg0 + (size_t)(kt2 + 1) * 64 * DH_);
            kreg1 = *(const short8*)(kg1 + (size_t)(kt2 + 1) * 64 * DH_);
            vreg0 = *(const short8*)(vg0 + (size_t)(kt2 + 1) * 64);
            vreg1 = *(const short8*)(vg1 + (size_t)(kt2 + 1) * 64);
        }
        // per row-group: S^T = K Q^T, softmax, pack P (pb); K frags re-read per group
        short8 pb[2][2];
        #pragma unroll
        for (int ro = 0; ro < 2; ro++) {
            f32x4 s[4];
            #pragma unroll
            for (int cb = 0; cb < 4; cb++) {
                s[cb] = (f32x4){0.f, 0.f, 0.f, 0.f};
                int key = cb * 16 + lr;
                #pragma unroll
                for (int ks = 0; ks < 2; ks++) {
                    int bytecol = ks * 64 + lg * 16;
                    short8 kf = *(const short8*)((char*)Kl + key * 128 + (bytecol ^ ((key & 7) << 4)));
                    s[cb] = __builtin_amdgcn_mfma_f32_16x16x32_bf16(kf, qf[ro][ks], s[cb], 0, 0, 0);
                }
            }
            // row max: 15 in-lane + 2 shfl
            float mx = fmaxf(fmaxf(fmaxf(s[0][0], s[0][1]), fmaxf(s[0][2], s[0][3])),
                             fmaxf(fmaxf(s[1][0], s[1][1]), fmaxf(s[1][2], s[1][3])));
            mx = fmaxf(mx, fmaxf(fmaxf(fmaxf(s[2][0], s[2][1]), fmaxf(s[2][2], s[2][3])),
                                 fmaxf(fmaxf(s[3][0], s[3][1]), fmaxf(s[3][2], s[3][3]))));
            mx = fmaxf(mx, __shfl_xor(mx, 16));
            mx = fmaxf(mx, __shfl_xor(mx, 32));
            // exact defer-max
            if (__any(mx > mi[ro])) {
                float mn = fmaxf(mi[ro], mx);
                float al = exp2f(mi[ro] - mn);
                mi[ro] = mn;
                li[ro] *= al;
                #pragma unroll
                for (int db = 0; db < 4; db++) oaccT[ro][db] *= al;
            }
            // P = exp2(S - m), row sum
            float rs = 0.f;
            #pragma unroll
            for (int cb = 0; cb < 4; cb++)
                #pragma unroll
                for (int i = 0; i < 4; i++) {
                    float p = exp2f(s[cb][i] - mi[ro]);
                    s[cb][i] = p;
                    rs += p;
                }
            rs += __shfl_xor(rs, 16);
            rs += __shfl_xor(rs, 32);
            li[ro] += rs;
            // pack P as PV B-operand: slot (ks,lg,j) -> key (ks*2+(j>>2))*16+lg*4+(j&3)
            #pragma unroll
            for (int ks = 0; ks < 2; ks++)
                #pragma unroll
                for (int i = 0; i < 4; i++) {
                    pb[ro][ks][i]     = (short)f2bf(s[2*ks][i]);
                    pb[ro][ks][i + 4] = (short)f2bf(s[2*ks + 1][i]);
                }
        }
        // O^T += V^T P^T: each vf read ONCE, feeds both row-groups
        #pragma unroll
        for (int ks = 0; ks < 2; ks++) {
            #pragma unroll
            for (int db = 0; db < 4; db++) {
                int dh = db * 16 + lr;
                int swz = (dh & 7) << 4;
                short4v v0 = *(const short4v*)((char*)Vl + dh * 128 + ((ks * 64 + lg * 8) ^ swz));
                short4v v1 = *(const short4v*)((char*)Vl + dh * 128 + ((ks * 64 + 32 + lg * 8) ^ swz));
                short8 vf;
                #pragma unroll
                for (int i = 0; i < 4; i++) { vf[i] = v0[i]; vf[i + 4] = v1[i]; }
                oaccT[0][db] = __builtin_amdgcn_mfma_f32_16x16x32_bf16(vf, pb[0][ks], oaccT[0][db], 0, 0, 0);
                oaccT[1][db] = __builtin_amdgcn_mfma_f32_16x16x32_bf16(vf, pb[1][ks], oaccT[1][db], 0, 0, 0);
            }
        }
    }
    // write: group ro -> row qrow(ro); cols h*64 + db*16 + lg*4 + {0..3} (8B packed)
    #pragma unroll
    for (int ro = 0; ro < 2; ro++) {
        float inv = 1.0f / li[ro];
        int qrow = qt * 128 + wave * 32 + ro * 16 + lr;
        unsigned short* orow = o + ((size_t)b * N_ + qrow) * C_ + h * 64;
        #pragma unroll
        for (int db = 0; db < 4; db++) {
            ushort4v pk;
            #pragma unroll
            for (int i = 0; i < 4; i++) pk[i] = f2bf(oaccT[ro][db][i] * inv);
            *(ushort4v*)(orow + db * 16 + lg * 4) = pk;
        }
    }
}

extern "C" void kernel_launch(void* const* d_in, const int* in_sizes, int n_in,
                              void* d_out, int out_size, void* d_ws, size_t ws_size,
                              hipStream_t stream) {
    (void)in_sizes; (void)n_in; (void)out_size; (void)ws_size;
    const float* x      = (const float*)d_in[0];
    const float* ln1_g  = (const float*)d_in[1];
    const float* ln1_b  = (const float*)d_in[2];
    const float* w_qkv  = (const float*)d_in[3];
    const float* w_proj = (const float*)d_in[4];
    const float* b_proj = (const float*)d_in[5];
    const float* ln2_g  = (const float*)d_in[6];
    const float* ln2_b  = (const float*)d_in[7];
    const float* w1     = (const float*)d_in[8];
    const float* b1     = (const float*)d_in[9];
    const float* w2     = (const float*)d_in[10];
    const float* b2     = (const float*)d_in[11];
    float* out = (float*)d_out;

    char* ws = (char*)d_ws;
    size_t off = 0;
    auto alloc = [&](size_t bytes) {
        char* p = ws + off;
        off += (bytes + 255) & ~(size_t)255;
        return p;
    };
    unsigned short* hb     = (unsigned short*)alloc((size_t)ROWS_ * C_ * 2);
    unsigned short* wqkvT  = (unsigned short*)alloc((size_t)C_ * 3 * C_ * 2);
    unsigned short* wprojT = (unsigned short*)alloc((size_t)C_ * C_ * 2);
    unsigned short* w1T    = (unsigned short*)alloc((size_t)C_ * HID_ * 2);
    unsigned short* w2T    = (unsigned short*)alloc((size_t)HID_ * C_ * 2);
    unsigned short* uni    = (unsigned short*)alloc((size_t)ROWS_ * HID_ * 2); // q/k/vt/o alias mid
    unsigned short* qb  = uni;
    unsigned short* kb  = qb  + (size_t)B_ * H_ * N_ * DH_;
    unsigned short* vtb = kb  + (size_t)B_ * H_ * N_ * DH_;
    unsigned short* ob  = vtb + (size_t)B_ * H_ * N_ * DH_;
    unsigned short* mid = uni;   // reuse after attention is done

    // weight convert+transpose (bf16, [out][in])
    convT_kernel<<<dim3(3 * C_ / 32, C_ / 32), 256, 0, stream>>>(w_qkv, wqkvT, C_, 3 * C_);
    convT_kernel<<<dim3(C_ / 32, C_ / 32), 256, 0, stream>>>(w_proj, wprojT, C_, C_);
    convT_kernel<<<dim3(HID_ / 32, C_ / 32), 256, 0, stream>>>(w1, w1T, C_, HID_);
    convT_kernel<<<dim3(C_ / 32, HID_ / 32), 256, 0, stream>>>(w2, w2T, HID_, C_);

    // LN1 -> hb
    ln_kernel<<<ROWS_, 256, 0, stream>>>(x, ln1_g, ln1_b, hb);
    // QK GEMM (N=1536), scatter to q(scaled)/k
    gemm_kernel<0><<<dim3(2 * C_ / 128, ROWS_ / 128), 256, 0, stream>>>(
        hb, wqkvT, C_, 2 * C_, nullptr, nullptr, nullptr, qb, kb);
    // V^T GEMM: A = W_v^T (wqkvT rows 1536..2304), Bt = hb per batch -> vtb coalesced
    gemm_kernel<3><<<dim3(N_ / 128, C_ / 128, B_), 256, 0, stream>>>(
        wqkvT + (size_t)2 * C_ * C_, hb, C_, N_, nullptr, nullptr, (void*)vtb, nullptr, nullptr);
    // attention -> ob  (1D grid 768, XCD-chunked, 128 q-rows/block)
    attn_kernel<<<dim3(8 * 6 * (N_ / 128)), 256, 0, stream>>>(qb, kb, vtb, ob);
    // proj + bias + residual -> d_out (f32 x1)
    gemm_kernel<1><<<dim3(C_ / 128, ROWS_ / 128), 256, 0, stream>>>(
        ob, wprojT, C_, C_, b_proj, x, (void*)out, nullptr, nullptr);
    // LN2 -> hb
    ln_kernel<<<ROWS_, 256, 0, stream>>>(out, ln2_g, ln2_b, hb);
    // MLP1 + gelu -> mid (bf16)
    gemm_kernel<2><<<dim3(HID_ / 128, ROWS_ / 128), 256, 0, stream>>>(
        hb, w1T, C_, HID_, b1, nullptr, (void*)mid, nullptr, nullptr);
    // MLP2 + bias + residual -> d_out
    gemm_kernel<1><<<dim3(C_ / 128, ROWS_ / 128), 256, 0, stream>>>(
        mid, w2T, HID_, C_, b2, out, (void*)out, nullptr, nullptr);
}